// Round 1
// baseline (26330.057 us; speedup 1.0000x reference)
//
#include <hip/hip_runtime.h>
#include <stdint.h>

// GRU encoder: VOCAB=50257, EMBED=HIDDEN=1024, SEQ=4096.
// Phase 1: x-projections xr/xz/xh = gather(emb,seq) @ {Wrx,Wzx,Wx}^T  (parallel GEMMs)
// Phase 2: 4096-step sequential scan, 128 persistent WGs, weights in VGPRs,
//          barrier-free dataflow via (tag|value) 64-bit agent-scope atomic cells.

#define HID    1024
#define SEQLEN 4096
#define NWG    128
#define RPW    8      // hidden rows owned per workgroup (1024/128)
#define BLOCK  256

typedef unsigned long long u64;

// ---------------------------------------------------------------------------
// Phase 1: C[t,i] = sum_e emb[seq[t],e] * W[i,e]   (both row-major, dot over e)
// grid (HID/64, SEQLEN/64, 3), block 256, 64x64 tile, BK=32, 4x4 per thread.
// ---------------------------------------------------------------------------
__global__ __launch_bounds__(BLOCK) void proj_gemm(
    const int* __restrict__ seq, const float* __restrict__ emb,
    const float* __restrict__ Wrx, const float* __restrict__ Wzx,
    const float* __restrict__ Wx,
    float* __restrict__ xr, float* __restrict__ xz, float* __restrict__ xh)
{
  __shared__ float As[32][68];   // [k][t], pad 68 keeps float4 alignment, breaks worst conflicts
  __shared__ float Bs[32][68];   // [k][i]
  __shared__ int   idx[64];

  const float* W = (blockIdx.z == 0) ? Wrx : (blockIdx.z == 1) ? Wzx : Wx;
  float*       C = (blockIdx.z == 0) ? xr  : (blockIdx.z == 1) ? xz  : xh;

  const int tid = threadIdx.x;
  const int t0 = blockIdx.y * 64;
  const int i0 = blockIdx.x * 64;
  if (tid < 64) idx[tid] = seq[t0 + tid];
  __syncthreads();

  float acc[4][4] = {};
  const int tx = tid & 15, ty = tid >> 4;   // 16x16 threads, 4x4 outputs each
  const int c4 = (tid & 7) * 4;             // k-subcolumn for loads
  const int r8 = tid >> 3;                  // row 0..31 for loads

  for (int k0 = 0; k0 < HID; k0 += 32) {
    for (int l = 0; l < 2; ++l) {
      const int rr = r8 + l * 32;
      float4 av = *(const float4*)(emb + (size_t)idx[rr] * HID + k0 + c4);
      As[c4+0][rr]=av.x; As[c4+1][rr]=av.y; As[c4+2][rr]=av.z; As[c4+3][rr]=av.w;
      float4 bv = *(const float4*)(W + (size_t)(i0 + rr) * HID + k0 + c4);
      Bs[c4+0][rr]=bv.x; Bs[c4+1][rr]=bv.y; Bs[c4+2][rr]=bv.z; Bs[c4+3][rr]=bv.w;
    }
    __syncthreads();
    #pragma unroll
    for (int k = 0; k < 32; ++k) {
      float a[4], b[4];
      *(float4*)a = *(const float4*)&As[k][ty * 4];
      *(float4*)b = *(const float4*)&Bs[k][tx * 4];
      #pragma unroll
      for (int i = 0; i < 4; ++i)
        #pragma unroll
        for (int j = 0; j < 4; ++j)
          acc[i][j] = fmaf(a[i], b[j], acc[i][j]);
    }
    __syncthreads();
  }
  #pragma unroll
  for (int i = 0; i < 4; ++i) {
    float4 v = make_float4(acc[i][0], acc[i][1], acc[i][2], acc[i][3]);
    *(float4*)(C + (size_t)(t0 + ty * 4 + i) * HID + i0 + tx * 4) = v;
  }
}

// ---------------------------------------------------------------------------
// Phase 2 helpers: 64-bit self-synchronizing cells, tag in high 32 bits.
// Relaxed agent-scope atomics: value+tag move in ONE atomic, no fences needed.
// ---------------------------------------------------------------------------
__device__ __forceinline__ u64 pack_cell(float v, unsigned tag) {
  return ((u64)tag << 32) | (u64)__float_as_uint(v);
}

__device__ __forceinline__ void poll4(const u64* __restrict__ cells, int j0,
                                      unsigned want, float v[4], int* budget) {
  u64 c0 = 0, c1 = 0, c2 = 0, c3 = 0;
  bool d0 = false, d1 = false, d2 = false, d3 = false;
  for (;;) {
    if (!d0) { c0 = __hip_atomic_load(&cells[j0+0], __ATOMIC_RELAXED, __HIP_MEMORY_SCOPE_AGENT); d0 = (unsigned)(c0 >> 32) == want; }
    if (!d1) { c1 = __hip_atomic_load(&cells[j0+1], __ATOMIC_RELAXED, __HIP_MEMORY_SCOPE_AGENT); d1 = (unsigned)(c1 >> 32) == want; }
    if (!d2) { c2 = __hip_atomic_load(&cells[j0+2], __ATOMIC_RELAXED, __HIP_MEMORY_SCOPE_AGENT); d2 = (unsigned)(c2 >> 32) == want; }
    if (!d3) { c3 = __hip_atomic_load(&cells[j0+3], __ATOMIC_RELAXED, __HIP_MEMORY_SCOPE_AGENT); d3 = (unsigned)(c3 >> 32) == want; }
    if (d0 & d1 & d2 & d3) break;
    if (--(*budget) <= 0) break;   // anti-hang bail-out: fails absmax instead of deadlocking
  }
  v[0] = __uint_as_float((unsigned)c0);
  v[1] = __uint_as_float((unsigned)c1);
  v[2] = __uint_as_float((unsigned)c2);
  v[3] = __uint_as_float((unsigned)c3);
}

// ---------------------------------------------------------------------------
// Phase 2: persistent scan. 128 WGs x 256 threads. WG g owns rows [8g, 8g+8).
// Wave w (of 4) owns rows 8g+2w, 8g+2w+1; lane l covers h-columns [16l,16l+16).
// All three recurrent weight rows live in VGPRs (3 mats x 2 rows x 16 cols).
// Per step: exchange h -> gates z,r -> publish r*h -> exchange rh -> candidate.
// ---------------------------------------------------------------------------
__global__ __launch_bounds__(BLOCK) void rnn_scan(
    const float* __restrict__ Wzh, const float* __restrict__ Wrh,
    const float* __restrict__ Whh,
    const float* __restrict__ xz, const float* __restrict__ xr,
    const float* __restrict__ xh,
    u64* __restrict__ hcell,    // [2][HID]
    u64* __restrict__ rhcell,   // [2][HID]
    float* __restrict__ out)
{
  const int tid  = threadIdx.x;
  const int wave = tid >> 6, lane = tid & 63;
  const int g    = blockIdx.x;
  const int r0   = g * RPW;
  const int rowA = r0 + wave * 2;        // this wave's two rows
  const int j0   = tid * 4;              // this thread's 4 exchange cells

  __shared__ float h_lds[HID];
  __shared__ float rh_lds[HID];

  // Preload weights into registers: wgt[mat][rowpair][c], col = lane*16 + c.
  float wgt[3][2][16];
  #pragma unroll
  for (int m = 0; m < 3; ++m) {
    const float* Wm = (m == 0) ? Wzh : (m == 1) ? Wrh : Whh;
    #pragma unroll
    for (int rr = 0; rr < 2; ++rr) {
      const float* p = Wm + (size_t)(rowA + rr) * HID + lane * 16;
      #pragma unroll
      for (int c = 0; c < 16; c += 4) {
        float4 v = *(const float4*)(p + c);
        wgt[m][rr][c+0] = v.x; wgt[m][rr][c+1] = v.y;
        wgt[m][rr][c+2] = v.z; wgt[m][rr][c+3] = v.w;
      }
    }
  }

  int budget = 1 << 22;
  float xzv[2], xrv[2], xhv[2], zv[2];

  for (int t = 1; t <= SEQLEN; ++t) {
    const u64* hsrc = hcell + ((t - 1) & 1) * HID;
    u64* rdst = rhcell + (t & 1) * HID;

    // x-projection rows for this step: issued early, hidden under the h-poll.
    if (lane == 0) {
      #pragma unroll
      for (int rr = 0; rr < 2; ++rr) {
        xzv[rr] = xz[(size_t)(t - 1) * HID + rowA + rr];
        xrv[rr] = xr[(size_t)(t - 1) * HID + rowA + rr];
        xhv[rr] = xh[(size_t)(t - 1) * HID + rowA + rr];
      }
    }

    // ---- exchange 1: fetch h_{t-1} ----
    float hv[4];
    poll4(hsrc, j0, (unsigned)(t - 1), hv, &budget);
    *(float4*)&h_lds[j0] = make_float4(hv[0], hv[1], hv[2], hv[3]);
    __syncthreads();

    // gate dots: az/ar over this lane's 16 columns, then wave-reduce.
    float hr[16];
    #pragma unroll
    for (int c = 0; c < 16; c += 4)
      *(float4*)&hr[c] = *(const float4*)&h_lds[lane * 16 + c];
    float az[2] = {0.f, 0.f}, ar[2] = {0.f, 0.f};
    #pragma unroll
    for (int rr = 0; rr < 2; ++rr)
      #pragma unroll
      for (int c = 0; c < 16; ++c) {
        az[rr] = fmaf(wgt[0][rr][c], hr[c], az[rr]);
        ar[rr] = fmaf(wgt[1][rr][c], hr[c], ar[rr]);
      }
    #pragma unroll
    for (int m = 1; m < 64; m <<= 1) {
      az[0] += __shfl_xor(az[0], m, 64);
      az[1] += __shfl_xor(az[1], m, 64);
      ar[0] += __shfl_xor(ar[0], m, 64);
      ar[1] += __shfl_xor(ar[1], m, 64);
    }
    if (lane == 0) {
      #pragma unroll
      for (int rr = 0; rr < 2; ++rr) {
        zv[rr]    = 1.f / (1.f + __expf(-(xzv[rr] + az[rr])));
        float rg  = 1.f / (1.f + __expf(-(xrv[rr] + ar[rr])));
        float rh  = rg * h_lds[rowA + rr];
        __hip_atomic_store(&rdst[rowA + rr], pack_cell(rh, (unsigned)t),
                           __ATOMIC_RELAXED, __HIP_MEMORY_SCOPE_AGENT);
      }
    }

    // ---- exchange 2: fetch (r*h)_t ----
    float rv[4];
    poll4(rdst, j0, (unsigned)t, rv, &budget);
    *(float4*)&rh_lds[j0] = make_float4(rv[0], rv[1], rv[2], rv[3]);
    __syncthreads();

    float rr16[16];
    #pragma unroll
    for (int c = 0; c < 16; c += 4)
      *(float4*)&rr16[c] = *(const float4*)&rh_lds[lane * 16 + c];
    float ac[2] = {0.f, 0.f};
    #pragma unroll
    for (int rr = 0; rr < 2; ++rr)
      #pragma unroll
      for (int c = 0; c < 16; ++c)
        ac[rr] = fmaf(wgt[2][rr][c], rr16[c], ac[rr]);
    #pragma unroll
    for (int m = 1; m < 64; m <<= 1) {
      ac[0] += __shfl_xor(ac[0], m, 64);
      ac[1] += __shfl_xor(ac[1], m, 64);
    }
    if (lane == 0) {
      #pragma unroll
      for (int rr = 0; rr < 2; ++rr) {
        float cand  = tanhf(xhv[rr] + ac[rr]);
        float hprev = h_lds[rowA + rr];
        float hn    = zv[rr] * hprev + (1.f - zv[rr]) * cand;
        __hip_atomic_store(&hcell[(t & 1) * HID + rowA + rr],
                           pack_cell(hn, (unsigned)t),
                           __ATOMIC_RELAXED, __HIP_MEMORY_SCOPE_AGENT);
        if (t == SEQLEN) out[rowA + rr] = hn;
      }
    }
    __syncthreads();   // protect h_lds/rh_lds before next step overwrites
  }
}

// ---------------------------------------------------------------------------
extern "C" void kernel_launch(void* const* d_in, const int* in_sizes, int n_in,
                              void* d_out, int out_size, void* d_ws, size_t ws_size,
                              hipStream_t stream) {
  (void)in_sizes; (void)n_in; (void)out_size; (void)ws_size;

  const int*   seq = (const int*)d_in[0];
  const float* emb = (const float*)d_in[1];
  const float* Wrx = (const float*)d_in[2];
  const float* Wrh = (const float*)d_in[3];
  const float* Wzx = (const float*)d_in[4];
  const float* Wzh = (const float*)d_in[5];
  const float* Wx  = (const float*)d_in[6];
  const float* Wh  = (const float*)d_in[7];

  char* ws = (char*)d_ws;
  const size_t PROJ = (size_t)SEQLEN * HID * sizeof(float);   // 16 MB each
  float* xr = (float*)(ws);
  float* xz = (float*)(ws + PROJ);
  float* xh = (float*)(ws + 2 * PROJ);
  u64* hcell  = (u64*)(ws + 3 * PROJ);                        // [2][HID]
  u64* rhcell = (u64*)(ws + 3 * PROJ + 2 * HID * sizeof(u64));

  // Reset exchange-cell tags every launch (replay-safe, poison-safe):
  // 0xFF.. = sentinel tag; then slot 0 of h = tag 0 / value 0.0f  (h_0 = zeros).
  hipMemsetAsync(hcell, 0xFF, 4 * HID * sizeof(u64), stream);
  hipMemsetAsync(hcell, 0x00, HID * sizeof(u64), stream);

  proj_gemm<<<dim3(HID / 64, SEQLEN / 64, 3), BLOCK, 0, stream>>>(
      seq, emb, Wrx, Wzx, Wx, xr, xz, xh);

  rnn_scan<<<dim3(NWG), BLOCK, 0, stream>>>(
      Wzh, Wrh, Wh, xz, xr, xh, hcell, rhcell, (float*)d_out);
}